// Round 5
// baseline (384.597 us; speedup 1.0000x reference)
//
#include <hip/hip_runtime.h>
#include <math.h>
#include <float.h>

#define NN 20000
#define EE 320000
#define INDIM 16
#define HID 50
#define TW 5
#define FO 10
#define NGROUPS 64

typedef float f4 __attribute__((ext_vector_type(4)));
typedef float f2 __attribute__((ext_vector_type(2)));

__device__ inline f4 f4_min(f4 a, f4 b) {
    f4 r; r.x = fminf(a.x, b.x); r.y = fminf(a.y, b.y);
    r.z = fminf(a.z, b.z); r.w = fminf(a.w, b.w); return r;
}
__device__ inline f4 f4_max(f4 a, f4 b) {
    f4 r; r.x = fmaxf(a.x, b.x); r.y = fmaxf(a.y, b.y);
    r.z = fmaxf(a.z, b.z); r.w = fmaxf(a.w, b.w); return r;
}
__device__ inline float sh3sum(float v, int g0, int G_) {
    return v + __shfl(v, g0 + G_, 64) + __shfl(v, g0 + 2 * G_, 64);
}
__device__ inline float sh3min(float v, int g0, int G_) {
    return fminf(fminf(v, __shfl(v, g0 + G_, 64)), __shfl(v, g0 + 2 * G_, 64));
}
__device__ inline float sh3max(float v, int g0, int G_) {
    return fmaxf(fmaxf(v, __shfl(v, g0 + G_, 64)), __shfl(v, g0 + 2 * G_, 64));
}
__device__ inline void acc4(float& acc, f4 w, float a0, float a1, float a2, float a3) {
    acc += w.x * a0; acc += w.y * a1; acc += w.z * a2; acc += w.w * a3;
}

// ---------- CSR build ----------
__global__ void k_deg(const int* __restrict__ dst, int* __restrict__ deg) {
    int e = blockIdx.x * 256 + threadIdx.x;
    if (e < EE) atomicAdd(&deg[dst[e]], 1);
}

__global__ void k_scan(const int* __restrict__ deg, int* __restrict__ offsets,
                       float* __restrict__ scal) {
    __shared__ int part[1024];
    __shared__ float fred[1024];
    const int CH = 20;
    int tid = threadIdx.x;
    int base = tid * CH;
    int loc[CH];
    int s = 0; float fs = 0.f;
    for (int c = 0; c < CH; ++c) {
        int idx = base + c;
        int v = (idx < NN) ? deg[idx] : 0;
        loc[c] = s; s += v;
        if (idx < NN) fs += logf((float)v + 1.0f);
    }
    part[tid] = s; fred[tid] = fs; __syncthreads();
    for (int off = 1; off < 1024; off <<= 1) {
        int v = (tid >= off) ? part[tid - off] : 0;
        __syncthreads();
        part[tid] += v;
        __syncthreads();
    }
    int pre = (tid > 0) ? part[tid - 1] : 0;
    for (int c = 0; c < CH; ++c) {
        int idx = base + c;
        if (idx < NN) offsets[idx] = pre + loc[c];
    }
    if (tid == 0) offsets[NN] = part[1023];
    for (int off = 512; off > 0; off >>= 1) {
        if (tid < off) fred[tid] += fred[tid + off];
        __syncthreads();
    }
    if (tid == 0) scal[0] = fred[0] / (float)NN;
}

__global__ void k_fill(const int* __restrict__ src, const int* __restrict__ dst,
                       const int* __restrict__ offsets, int* __restrict__ cursor,
                       int* __restrict__ csr_src) {
    int e = blockIdx.x * 256 + threadIdx.x;
    if (e < EE) {
        int d = dst[e];
        int pos = offsets[d] + atomicAdd(&cursor[d], 1);
        csr_src[pos] = src[e];
    }
}

// ---------- pack all weight layouts in one kernel ----------
__global__ void k_pack(const float* __restrict__ preW0, const float* __restrict__ preW1,
                       const float* __restrict__ postW0, const float* __restrict__ postW1,
                       const float* __restrict__ linW0, const float* __restrict__ linW1,
                       float* __restrict__ preWt0, float* __restrict__ preWt1,
                       float* __restrict__ Wx0, float* __restrict__ Wid0,
                       float* __restrict__ Wamp0, float* __restrict__ Watt0,
                       float* __restrict__ Wx1, float* __restrict__ Wid1,
                       float* __restrict__ Wamp1, float* __restrict__ Watt1,
                       float* __restrict__ Lt0, float* __restrict__ Lt1) {
    int idx = blockIdx.x * 256 + threadIdx.x;
    int job = blockIdx.y;
    int q = idx >> 8, k = (idx >> 2) & 63, j = idx & 3;
    switch (job) {
    case 0:
        if (idx < 32 * 80) { int c = idx / 80, r = idx % 80; preWt0[idx] = preW0[r * 32 + c]; }
        break;
    case 1:
        if (idx < 100 * 256) { int c = idx / 256, r = idx % 256; preWt1[idx] = (r < 250) ? preW1[r * 100 + c] : 0.f; }
        break;
    case 2:
        if (idx < 4 * 256) { int f = q * 4 + j; Wx0[idx] = (k < HID) ? postW0[k * 208 + f] : 0.f; }
        break;
    case 3:
        if (idx < 16 * 256) { int s = q / 4, f = (q % 4) * 4 + j; Wid0[idx] = (k < HID) ? postW0[k * 208 + (1 + s) * 16 + f] : 0.f; }
        break;
    case 4:
        if (idx < 16 * 256) { int s = q / 4, f = (q % 4) * 4 + j; Wamp0[idx] = (k < HID) ? postW0[k * 208 + (5 + s) * 16 + f] : 0.f; }
        break;
    case 5:
        if (idx < 16 * 256) { int s = q / 4, f = (q % 4) * 4 + j; Watt0[idx] = (k < HID) ? postW0[k * 208 + (9 + s) * 16 + f] : 0.f; }
        break;
    case 6:
        if (idx < 13 * 256) { int f = q * 4 + j; Wx1[idx] = (f < 50 && k < HID) ? postW1[k * 650 + f] : 0.f; }
        break;
    case 7:
        if (idx < 52 * 256) { int s = q / 13, f = (q % 13) * 4 + j; Wid1[idx] = (f < 50 && k < HID) ? postW1[k * 650 + (1 + s) * 50 + f] : 0.f; }
        break;
    case 8:
        if (idx < 52 * 256) { int s = q / 13, f = (q % 13) * 4 + j; Wamp1[idx] = (f < 50 && k < HID) ? postW1[k * 650 + (5 + s) * 50 + f] : 0.f; }
        break;
    case 9:
        if (idx < 52 * 256) { int s = q / 13, f = (q % 13) * 4 + j; Watt1[idx] = (f < 50 && k < HID) ? postW1[k * 650 + (9 + s) * 50 + f] : 0.f; }
        break;
    case 10:
        if (idx < 13 * 256) { int f = q * 4 + j; Lt0[idx] = (f < 50 && k < HID) ? linW0[k * 50 + f] : 0.f; }
        break;
    case 11:
        if (idx < 13 * 256) { int f = q * 4 + j; Lt1[idx] = (f < 50 && k < HID) ? linW1[k * 50 + f] : 0.f; }
        break;
    }
}

// ---------- C = x@WL^T + b, P = x@WR^T with transposed weights preWt[2F][TFP] ----------
template <int F, int TF, int TFP>
__global__ __launch_bounds__(256, 4) void k_gemm_CP(
    const float* __restrict__ x, const float* __restrict__ preWt,
    const float* __restrict__ b,
    float* __restrict__ C, float* __restrict__ P) {
    const int NODES = 16;
    __shared__ float xs[NODES * F];
    int tid = threadIdx.x;
    int base = blockIdx.x * NODES;
    for (int idx = tid; idx < NODES * F; idx += 256) xs[idx] = x[(size_t)base * F + idx];
    __syncthreads();
    if (tid < TF) {
        float accC[NODES], accP[NODES];
#pragma unroll
        for (int n = 0; n < NODES; ++n) { accC[n] = 0.f; accP[n] = 0.f; }
        for (int f = 0; f < F; ++f) {
            float wl = preWt[f * TFP + tid];
            float wr = preWt[(F + f) * TFP + tid];
#pragma unroll
            for (int n = 0; n < NODES; ++n) {
                float xv = xs[n * F + f];
                accC[n] += xv * wl;
                accP[n] += xv * wr;
            }
        }
        float bb = b[tid];
        for (int n = 0; n < NODES; ++n) {
            C[((size_t)(base + n)) * TFP + tid] = accC[n] + bb;
            P[((size_t)(base + n)) * TFP + tid] = accP[n];
        }
    } else if (tid < TFP) {
        for (int n = 0; n < NODES; ++n) {
            C[((size_t)(base + n)) * TFP + tid] = 0.f;
            P[((size_t)(base + n)) * TFP + tid] = 0.f;
        }
    }
}

// ---------- gather: stats per node -> global agg[n][4][TFP], registers only ----------
template <int F, int TFP, int EP, int XSTR>
__global__ __launch_bounds__(256) void k_gather(
    const float* __restrict__ xin, const float* __restrict__ C, const float* __restrict__ P,
    const int* __restrict__ offsets, const int* __restrict__ csr,
    float* __restrict__ agg, float* __restrict__ xp) {
    const int G = TFP / 4;
    int t = threadIdx.x;
    int w = t >> 6, lane = t & 63;
    int i = blockIdx.x * 4 + w;
    int beg = offsets[i], end = offsets[i + 1];
    int d = end - beg;
    int g = (EP == 1) ? lane : (lane % G);
    int e = (EP == 1) ? 0 : (lane / G);
    bool act = (EP == 1) ? (g < G) : (e < EP);
    f4 S = {0.f, 0.f, 0.f, 0.f}, S2 = {0.f, 0.f, 0.f, 0.f};
    f4 MN = {FLT_MAX, FLT_MAX, FLT_MAX, FLT_MAX};
    f4 MX = {-FLT_MAX, -FLT_MAX, -FLT_MAX, -FLT_MAX};
    const f4* __restrict__ Pv = (const f4*)P;
    if (act) {
        if (EP == 1) {
            int j = beg;
            for (; j + 4 <= end; j += 4) {
                int s0 = csr[j], s1 = csr[j + 1], s2 = csr[j + 2], s3 = csr[j + 3];
                f4 a = Pv[(size_t)s0 * G + g];
                f4 b = Pv[(size_t)s1 * G + g];
                f4 c = Pv[(size_t)s2 * G + g];
                f4 dd = Pv[(size_t)s3 * G + g];
                S += a; S2 += a * a; MN = f4_min(MN, a); MX = f4_max(MX, a);
                S += b; S2 += b * b; MN = f4_min(MN, b); MX = f4_max(MX, b);
                S += c; S2 += c * c; MN = f4_min(MN, c); MX = f4_max(MX, c);
                S += dd; S2 += dd * dd; MN = f4_min(MN, dd); MX = f4_max(MX, dd);
            }
            for (; j < end; ++j) {
                int s0 = csr[j];
                f4 a = Pv[(size_t)s0 * G + g];
                S += a; S2 += a * a; MN = f4_min(MN, a); MX = f4_max(MX, a);
            }
        } else {
            int j = beg + e;
            for (; j + EP < end; j += 2 * EP) {
                int s0 = csr[j], s1 = csr[j + EP];
                f4 a = Pv[(size_t)s0 * G + g];
                f4 b = Pv[(size_t)s1 * G + g];
                S += a; S2 += a * a; MN = f4_min(MN, a); MX = f4_max(MX, a);
                S += b; S2 += b * b; MN = f4_min(MN, b); MX = f4_max(MX, b);
            }
            if (j < end) {
                int s0 = csr[j];
                f4 a = Pv[(size_t)s0 * G + g];
                S += a; S2 += a * a; MN = f4_min(MN, a); MX = f4_max(MX, a);
            }
        }
    }
    if (EP == 3) {
        int g0 = lane % G;
        S.x = sh3sum(S.x, g0, G); S.y = sh3sum(S.y, g0, G);
        S.z = sh3sum(S.z, g0, G); S.w = sh3sum(S.w, g0, G);
        S2.x = sh3sum(S2.x, g0, G); S2.y = sh3sum(S2.y, g0, G);
        S2.z = sh3sum(S2.z, g0, G); S2.w = sh3sum(S2.w, g0, G);
        MN.x = sh3min(MN.x, g0, G); MN.y = sh3min(MN.y, g0, G);
        MN.z = sh3min(MN.z, g0, G); MN.w = sh3min(MN.w, g0, G);
        MX.x = sh3max(MX.x, g0, G); MX.y = sh3max(MX.y, g0, G);
        MX.z = sh3max(MX.z, g0, G); MX.w = sh3max(MX.w, g0, G);
    }
    if (lane < G) {
        f4 Cv = ((const f4*)C)[(size_t)i * G + lane];
        float degf = (float)d;
        float rdegc = 1.0f / fmaxf(degf, 1.0f);
        f4 mean, sq, var, stdv, mnv, mxv;
        mean.x = (degf * Cv.x + S.x) * rdegc; mean.y = (degf * Cv.y + S.y) * rdegc;
        mean.z = (degf * Cv.z + S.z) * rdegc; mean.w = (degf * Cv.w + S.w) * rdegc;
        sq.x = degf * Cv.x * Cv.x + 2.f * Cv.x * S.x + S2.x;
        sq.y = degf * Cv.y * Cv.y + 2.f * Cv.y * S.y + S2.y;
        sq.z = degf * Cv.z * Cv.z + 2.f * Cv.z * S.z + S2.z;
        sq.w = degf * Cv.w * Cv.w + 2.f * Cv.w * S.w + S2.w;
        var.x = sq.x * rdegc - mean.x * mean.x; var.y = sq.y * rdegc - mean.y * mean.y;
        var.z = sq.z * rdegc - mean.z * mean.z; var.w = sq.w * rdegc - mean.w * mean.w;
        stdv.x = sqrtf(fmaxf(var.x, 0.f) + 1e-5f); stdv.y = sqrtf(fmaxf(var.y, 0.f) + 1e-5f);
        stdv.z = sqrtf(fmaxf(var.z, 0.f) + 1e-5f); stdv.w = sqrtf(fmaxf(var.w, 0.f) + 1e-5f);
        if (d > 0) {
            mnv.x = Cv.x + MN.x; mnv.y = Cv.y + MN.y; mnv.z = Cv.z + MN.z; mnv.w = Cv.w + MN.w;
            mxv.x = Cv.x + MX.x; mxv.y = Cv.y + MX.y; mxv.z = Cv.z + MX.z; mxv.w = Cv.w + MX.w;
        } else {
            mnv = (f4){0.f, 0.f, 0.f, 0.f}; mxv = mnv;
        }
        f4* __restrict__ dstv = (f4*)(agg + (size_t)i * 4 * TFP);
        dstv[lane] = mean;
        dstv[G + lane] = mnv;
        dstv[2 * G + lane] = mxv;
        dstv[3 * G + lane] = stdv;
    }
    if (XSTR > 0 && lane < XSTR)
        xp[(size_t)i * XSTR + lane] = (lane < F) ? xin[(size_t)i * F + lane] : 0.f;
}

// ---------- post: dense per-node GEMM, 8 nodes/wave, lane = output k ----------
template <int F, int TFP, int SQ, int SQX, int XSTR, bool AF4>
__global__ __launch_bounds__(128) void k_post(
    const float* __restrict__ xsrc, const float* __restrict__ agg,
    const int* __restrict__ offsets, const float* __restrict__ scal,
    const float* __restrict__ Wx, const float* __restrict__ Wid,
    const float* __restrict__ Wamp, const float* __restrict__ Watt,
    const float* __restrict__ postb,
    const float* __restrict__ Lt, const float* __restrict__ linb,
    float* __restrict__ hout) {
    __shared__ __align__(16) float sY[2][8][52];
    int t = threadIdx.x;
    int w = t >> 6, lane = t & 63;
    int base = blockIdx.x * 16 + w * 8;
    int kk = (lane < HID) ? lane : (HID - 1);
    int tw = kk / FO;
    float rscal = 1.0f / scal[0];
    float amp[8], ia[8];
#pragma unroll
    for (int n = 0; n < 8; ++n) {
        int dd = offsets[base + n + 1] - offsets[base + n];
        float a = logf(fmaxf((float)dd, 1.f) + 1.f) * rscal;
        amp[n] = a; ia[n] = 1.0f / a;
    }
    float y0[8], y1[8], y2[8];
#pragma unroll
    for (int n = 0; n < 8; ++n) { y0[n] = 0.f; y1[n] = 0.f; y2[n] = 0.f; }
    const f4* __restrict__ Wxv = (const f4*)Wx;
    const f4* __restrict__ Wiv = (const f4*)Wid;
    const f4* __restrict__ Wav = (const f4*)Wamp;
    const f4* __restrict__ Wtv = (const f4*)Watt;
    // x part
    for (int q = 0; q < SQX; ++q) {
        f4 wv = Wxv[q * 64 + lane];
#pragma unroll
        for (int n = 0; n < 8; ++n) {
            f4 a = *(const f4*)(xsrc + (size_t)(base + n) * XSTR + 4 * q);
            acc4(y0[n], wv, a.x, a.y, a.z, a.w);
        }
    }
    // agg segments
    for (int s = 0; s < 4; ++s) {
        for (int q = 0; q < SQ; ++q) {
            f4 wi = Wiv[(s * SQ + q) * 64 + lane];
            f4 wa = Wav[(s * SQ + q) * 64 + lane];
            f4 wt = Wtv[(s * SQ + q) * 64 + lane];
#pragma unroll
            for (int n = 0; n < 8; ++n) {
                const float* __restrict__ Ab =
                    agg + ((size_t)(base + n) * 4 + s) * TFP + tw * F + 4 * q;
                float a0, a1, a2, a3;
                if constexpr (AF4) {
                    f4 av = *(const f4*)Ab;
                    a0 = av.x; a1 = av.y; a2 = av.z; a3 = av.w;
                } else {
                    f2 u = *(const f2*)Ab;
                    f2 v = *(const f2*)(Ab + 2);
                    a0 = u.x; a1 = u.y; a2 = v.x; a3 = v.y;
                }
                acc4(y0[n], wi, a0, a1, a2, a3);
                acc4(y1[n], wa, a0, a1, a2, a3);
                acc4(y2[n], wt, a0, a1, a2, a3);
            }
        }
    }
    float pb = postb[kk];
#pragma unroll
    for (int n = 0; n < 8; ++n) {
        float y = pb + y0[n] + amp[n] * y1[n] + ia[n] * y2[n];
        if (lane < HID) sY[w][n][lane] = y;
        else if (lane < 52) sY[w][n][lane] = 0.f;
    }
    // lin (wave-private LDS, no barrier)
    const f4* __restrict__ Lv = (const f4*)Lt;
    float o[8];
    float lb = linb[kk];
#pragma unroll
    for (int n = 0; n < 8; ++n) o[n] = lb;
    for (int q = 0; q < 13; ++q) {
        f4 lv = Lv[q * 64 + lane];
#pragma unroll
        for (int n = 0; n < 8; ++n) {
            f4 sv = *(const f4*)(&sY[w][n][4 * q]);
            acc4(o[n], lv, sv.x, sv.y, sv.z, sv.w);
        }
    }
    if (lane < HID) {
#pragma unroll
        for (int n = 0; n < 8; ++n)
            hout[(size_t)(base + n) * HID + lane] = o[n];
    }
}

// ---------- BN: one-pass partial sums + apply ----------
__global__ void k_bn_part(const float* __restrict__ h, float* __restrict__ acc) {
    __shared__ float ss[4][64], ss2[4][64];
    int t = threadIdx.x;
    int rs = t >> 6, c = t & 63;
    float s = 0.f, s2 = 0.f;
    if (c < HID) {
        int r0 = blockIdx.x * 200 + rs;
        int rend = blockIdx.x * 200 + 200;
        if (rend > NN) rend = NN;
        for (int r = r0; r < rend; r += 4) {
            float v = h[(size_t)r * HID + c];
            s += v; s2 += v * v;
        }
    }
    ss[rs][c] = s; ss2[rs][c] = s2;
    __syncthreads();
    if (t < HID) {
        float S = ss[0][t] + ss[1][t] + ss[2][t] + ss[3][t];
        float S2 = ss2[0][t] + ss2[1][t] + ss2[2][t] + ss2[3][t];
        atomicAdd(&acc[t], S);
        atomicAdd(&acc[64 + t], S2);
    }
}

__global__ void k_bn_relu(const float* __restrict__ hin, const float* __restrict__ acc,
                          const float* __restrict__ gamma, const float* __restrict__ beta,
                          float* __restrict__ hout) {
    int idx = blockIdx.x * 256 + threadIdx.x;
    if (idx < NN * HID) {
        int c = idx % HID;
        float mu = acc[c] * (1.f / NN);
        float var = acc[64 + c] * (1.f / NN) - mu * mu;
        float v = hin[idx];
        hout[idx] = fmaxf(gamma[c] * (v - mu) * rsqrtf(var + 1e-5f) + beta[c], 0.f);
    }
}

// ---------- fused bounds + pooling + head MLP ----------
__global__ void k_head(const float* __restrict__ h, const int* __restrict__ batch,
                       const float* __restrict__ W1, const float* __restrict__ b1,
                       const float* __restrict__ W2, const float* __restrict__ b2,
                       const float* __restrict__ W3, const float* __restrict__ b3,
                       float* __restrict__ out) {
    __shared__ float sp[HID], h1[50], h2[25];
    __shared__ int sbound[2];
    int g = blockIdx.x, tid = threadIdx.x;
    if (tid < 2) {
        int target = g + tid;
        int lo = 0, hi = NN;
        while (lo < hi) {
            int mid = (lo + hi) >> 1;
            if (batch[mid] < target) lo = mid + 1; else hi = mid;
        }
        sbound[tid] = lo;
    }
    __syncthreads();
    int beg = sbound[0], end = sbound[1];
    if (tid < HID) {
        float s0 = 0.f, s1 = 0.f, s2 = 0.f, s3 = 0.f;
        int n = beg;
        for (; n + 4 <= end; n += 4) {
            s0 += h[(size_t)n * HID + tid];
            s1 += h[(size_t)(n + 1) * HID + tid];
            s2 += h[(size_t)(n + 2) * HID + tid];
            s3 += h[(size_t)(n + 3) * HID + tid];
        }
        for (; n < end; ++n) s0 += h[(size_t)n * HID + tid];
        sp[tid] = (s0 + s1 + s2 + s3) / fmaxf((float)(end - beg), 1.0f);
    }
    __syncthreads();
    if (tid < 50) {
        float a = b1[tid];
        for (int k = 0; k < HID; ++k) a += W1[tid * HID + k] * sp[k];
        h1[tid] = fmaxf(a, 0.f);
    }
    __syncthreads();
    if (tid < 25) {
        float a = b2[tid];
        for (int k = 0; k < 50; ++k) a += W2[tid * 50 + k] * h1[k];
        h2[tid] = fmaxf(a, 0.f);
    }
    __syncthreads();
    if (tid == 0) {
        float a = b3[0];
        for (int k = 0; k < 25; ++k) a += W3[k] * h2[k];
        out[g] = a;
    }
}

extern "C" void kernel_launch(void* const* d_in, const int* in_sizes, int n_in,
                              void* d_out, int out_size, void* d_ws, size_t ws_size,
                              hipStream_t stream) {
    const float* x      = (const float*)d_in[0];
    const int*   ei     = (const int*)d_in[1];
    const int*   batch  = (const int*)d_in[2];
    const float* preW0  = (const float*)d_in[3];
    const float* preb0  = (const float*)d_in[4];
    const float* postW0 = (const float*)d_in[5];
    const float* postb0 = (const float*)d_in[6];
    const float* linW0  = (const float*)d_in[7];
    const float* linb0  = (const float*)d_in[8];
    const float* gamma0 = (const float*)d_in[9];
    const float* beta0  = (const float*)d_in[10];
    const float* preW1  = (const float*)d_in[11];
    const float* preb1  = (const float*)d_in[12];
    const float* postW1 = (const float*)d_in[13];
    const float* postb1 = (const float*)d_in[14];
    const float* linW1  = (const float*)d_in[15];
    const float* linb1  = (const float*)d_in[16];
    const float* gamma1 = (const float*)d_in[17];
    const float* beta1  = (const float*)d_in[18];
    const float* mW1    = (const float*)d_in[19];
    const float* mb1    = (const float*)d_in[20];
    const float* mW2    = (const float*)d_in[21];
    const float* mb2    = (const float*)d_in[22];
    const float* mW3    = (const float*)d_in[23];
    const float* mb3    = (const float*)d_in[24];
    float* out = (float*)d_out;
    (void)in_sizes; (void)n_in; (void)out_size; (void)ws_size;

    char* ws = (char*)d_ws;
    size_t off = 0;
    auto alloc = [&](size_t bytes) -> void* {
        void* p = ws + off;
        off += (bytes + 255) & ~(size_t)255;
        return p;
    };
    int*   deg     = (int*)alloc((size_t)NN * 4);
    int*   offsets = (int*)alloc((size_t)(NN + 1) * 4);
    int*   cursor  = (int*)alloc((size_t)NN * 4);
    int*   csr_src = (int*)alloc((size_t)EE * 4);
    float* scal    = (float*)alloc(64);
    float* bnacc0  = (float*)alloc(128 * 4);
    float* bnacc1  = (float*)alloc(128 * 4);
    float* preWt0  = (float*)alloc((size_t)32 * 80 * 4);
    float* preWt1  = (float*)alloc((size_t)100 * 256 * 4);
    float* Wx0     = (float*)alloc((size_t)4 * 256 * 4);
    float* Wid0    = (float*)alloc((size_t)16 * 256 * 4);
    float* Wamp0   = (float*)alloc((size_t)16 * 256 * 4);
    float* Watt0   = (float*)alloc((size_t)16 * 256 * 4);
    float* Wx1     = (float*)alloc((size_t)13 * 256 * 4);
    float* Wid1    = (float*)alloc((size_t)52 * 256 * 4);
    float* Wamp1   = (float*)alloc((size_t)52 * 256 * 4);
    float* Watt1   = (float*)alloc((size_t)52 * 256 * 4);
    float* Lt0     = (float*)alloc((size_t)13 * 256 * 4);
    float* Lt1     = (float*)alloc((size_t)13 * 256 * 4);
    float* Cbuf    = (float*)alloc((size_t)NN * 256 * 4);
    float* Pbuf    = (float*)alloc((size_t)NN * 256 * 4);
    float* h1buf   = (float*)alloc((size_t)NN * HID * 4);
    float* h2buf   = (float*)alloc((size_t)NN * HID * 4);
    float* aggbuf  = (float*)alloc((size_t)NN * 4 * 256 * 4);
    float* xp      = (float*)alloc((size_t)NN * 52 * 4);

    const int* src = ei;
    const int* dst = ei + EE;

    hipMemsetAsync(deg, 0, (size_t)NN * 4, stream);
    hipMemsetAsync(cursor, 0, (size_t)NN * 4, stream);
    hipMemsetAsync(bnacc0, 0, 128 * 4, stream);
    hipMemsetAsync(bnacc1, 0, 128 * 4, stream);

    k_pack<<<dim3(100, 12), 256, 0, stream>>>(preW0, preW1, postW0, postW1, linW0, linW1,
                                              preWt0, preWt1, Wx0, Wid0, Wamp0, Watt0,
                                              Wx1, Wid1, Wamp1, Watt1, Lt0, Lt1);
    k_deg<<<EE / 256, 256, 0, stream>>>(dst, deg);
    k_scan<<<1, 1024, 0, stream>>>(deg, offsets, scal);
    k_fill<<<EE / 256, 256, 0, stream>>>(src, dst, offsets, cursor, csr_src);

    // ---- conv0 (F=16, TFP=80) ----
    k_gemm_CP<INDIM, 80, 80><<<NN / 16, 256, 0, stream>>>(x, preWt0, preb0, Cbuf, Pbuf);
    k_gather<INDIM, 80, 3, 0><<<NN / 4, 256, 0, stream>>>(x, Cbuf, Pbuf, offsets, csr_src,
                                                          aggbuf, xp);
    k_post<INDIM, 80, 4, 4, 16, true><<<NN / 16, 128, 0, stream>>>(
        x, aggbuf, offsets, scal, Wx0, Wid0, Wamp0, Watt0, postb0, Lt0, linb0, h1buf);
    k_bn_part<<<100, 256, 0, stream>>>(h1buf, bnacc0);
    k_bn_relu<<<(NN * HID + 255) / 256, 256, 0, stream>>>(h1buf, bnacc0, gamma0, beta0, h1buf);

    // ---- conv1 (F=50, TFP=256) ----
    k_gemm_CP<HID, 250, 256><<<NN / 16, 256, 0, stream>>>(h1buf, preWt1, preb1, Cbuf, Pbuf);
    k_gather<HID, 256, 1, 52><<<NN / 4, 256, 0, stream>>>(h1buf, Cbuf, Pbuf, offsets, csr_src,
                                                          aggbuf, xp);
    k_post<HID, 256, 13, 13, 52, false><<<NN / 16, 128, 0, stream>>>(
        xp, aggbuf, offsets, scal, Wx1, Wid1, Wamp1, Watt1, postb1, Lt1, linb1, h2buf);
    k_bn_part<<<100, 256, 0, stream>>>(h2buf, bnacc1);
    k_bn_relu<<<(NN * HID + 255) / 256, 256, 0, stream>>>(h2buf, bnacc1, gamma1, beta1, h2buf);

    // ---- pool + head ----
    k_head<<<NGROUPS, 64, 0, stream>>>(h2buf, batch, mW1, mb1, mW2, mb2, mW3, mb3, out);
}

// Round 6
// 344.704 us; speedup vs baseline: 1.1157x; 1.1157x over previous
//
#include <hip/hip_runtime.h>
#include <math.h>
#include <float.h>

#define NN 20000
#define EE 320000
#define INDIM 16
#define HID 50
#define TW 5
#define FO 10
#define NGROUPS 64

typedef float f4 __attribute__((ext_vector_type(4)));
typedef float f2 __attribute__((ext_vector_type(2)));

__device__ inline f4 f4_min(f4 a, f4 b) {
    f4 r; r.x = fminf(a.x, b.x); r.y = fminf(a.y, b.y);
    r.z = fminf(a.z, b.z); r.w = fminf(a.w, b.w); return r;
}
__device__ inline f4 f4_max(f4 a, f4 b) {
    f4 r; r.x = fmaxf(a.x, b.x); r.y = fmaxf(a.y, b.y);
    r.z = fmaxf(a.z, b.z); r.w = fmaxf(a.w, b.w); return r;
}
__device__ inline float sh3sum(float v, int g0, int G_) {
    return v + __shfl(v, g0 + G_, 64) + __shfl(v, g0 + 2 * G_, 64);
}
__device__ inline float sh3min(float v, int g0, int G_) {
    return fminf(fminf(v, __shfl(v, g0 + G_, 64)), __shfl(v, g0 + 2 * G_, 64));
}
__device__ inline float sh3max(float v, int g0, int G_) {
    return fmaxf(fmaxf(v, __shfl(v, g0 + G_, 64)), __shfl(v, g0 + 2 * G_, 64));
}
__device__ inline void acc4(float& acc, f4 w, float a0, float a1, float a2, float a3) {
    acc += w.x * a0; acc += w.y * a1; acc += w.z * a2; acc += w.w * a3;
}

// ---------- CSR build ----------
__global__ void k_deg(const int* __restrict__ dst, int* __restrict__ deg) {
    int e = blockIdx.x * 256 + threadIdx.x;
    if (e < EE) atomicAdd(&deg[dst[e]], 1);
}

__global__ void k_scan(const int* __restrict__ deg, int* __restrict__ offsets,
                       float* __restrict__ scal) {
    __shared__ int part[1024];
    __shared__ float fred[1024];
    const int CH = 20;
    int tid = threadIdx.x;
    int base = tid * CH;
    int loc[CH];
    int s = 0; float fs = 0.f;
    for (int c = 0; c < CH; ++c) {
        int idx = base + c;
        int v = (idx < NN) ? deg[idx] : 0;
        loc[c] = s; s += v;
        if (idx < NN) fs += logf((float)v + 1.0f);
    }
    part[tid] = s; fred[tid] = fs; __syncthreads();
    for (int off = 1; off < 1024; off <<= 1) {
        int v = (tid >= off) ? part[tid - off] : 0;
        __syncthreads();
        part[tid] += v;
        __syncthreads();
    }
    int pre = (tid > 0) ? part[tid - 1] : 0;
    for (int c = 0; c < CH; ++c) {
        int idx = base + c;
        if (idx < NN) offsets[idx] = pre + loc[c];
    }
    if (tid == 0) offsets[NN] = part[1023];
    for (int off = 512; off > 0; off >>= 1) {
        if (tid < off) fred[tid] += fred[tid + off];
        __syncthreads();
    }
    if (tid == 0) scal[0] = fred[0] / (float)NN;
}

__global__ void k_fill(const int* __restrict__ src, const int* __restrict__ dst,
                       const int* __restrict__ offsets, int* __restrict__ cursor,
                       int* __restrict__ csr_src) {
    int e = blockIdx.x * 256 + threadIdx.x;
    if (e < EE) {
        int d = dst[e];
        int pos = offsets[d] + atomicAdd(&cursor[d], 1);
        csr_src[pos] = src[e];
    }
}

// ---------- pack all weight layouts in one kernel ----------
__global__ void k_pack(const float* __restrict__ preW0, const float* __restrict__ preW1,
                       const float* __restrict__ postW0, const float* __restrict__ postW1,
                       const float* __restrict__ linW0, const float* __restrict__ linW1,
                       float* __restrict__ preWt0, float* __restrict__ preWt1,
                       float* __restrict__ Wx0, float* __restrict__ Wid0,
                       float* __restrict__ Wamp0, float* __restrict__ Watt0,
                       float* __restrict__ Wx1, float* __restrict__ Wid1,
                       float* __restrict__ Wamp1, float* __restrict__ Watt1,
                       float* __restrict__ Lt0, float* __restrict__ Lt1) {
    int idx = blockIdx.x * 256 + threadIdx.x;
    int job = blockIdx.y;
    int q = idx >> 8, k = (idx >> 2) & 63, j = idx & 3;
    switch (job) {
    case 0:
        if (idx < 32 * 80) { int c = idx / 80, r = idx % 80; preWt0[idx] = preW0[r * 32 + c]; }
        break;
    case 1:
        if (idx < 100 * 256) { int c = idx / 256, r = idx % 256; preWt1[idx] = (r < 250) ? preW1[r * 100 + c] : 0.f; }
        break;
    case 2:
        if (idx < 4 * 256) { int f = q * 4 + j; Wx0[idx] = (k < HID) ? postW0[k * 208 + f] : 0.f; }
        break;
    case 3:
        if (idx < 16 * 256) { int s = q / 4, f = (q % 4) * 4 + j; Wid0[idx] = (k < HID) ? postW0[k * 208 + (1 + s) * 16 + f] : 0.f; }
        break;
    case 4:
        if (idx < 16 * 256) { int s = q / 4, f = (q % 4) * 4 + j; Wamp0[idx] = (k < HID) ? postW0[k * 208 + (5 + s) * 16 + f] : 0.f; }
        break;
    case 5:
        if (idx < 16 * 256) { int s = q / 4, f = (q % 4) * 4 + j; Watt0[idx] = (k < HID) ? postW0[k * 208 + (9 + s) * 16 + f] : 0.f; }
        break;
    case 6:
        if (idx < 13 * 256) { int f = q * 4 + j; Wx1[idx] = (f < 50 && k < HID) ? postW1[k * 650 + f] : 0.f; }
        break;
    case 7:
        if (idx < 52 * 256) { int s = q / 13, f = (q % 13) * 4 + j; Wid1[idx] = (f < 50 && k < HID) ? postW1[k * 650 + (1 + s) * 50 + f] : 0.f; }
        break;
    case 8:
        if (idx < 52 * 256) { int s = q / 13, f = (q % 13) * 4 + j; Wamp1[idx] = (f < 50 && k < HID) ? postW1[k * 650 + (5 + s) * 50 + f] : 0.f; }
        break;
    case 9:
        if (idx < 52 * 256) { int s = q / 13, f = (q % 13) * 4 + j; Watt1[idx] = (f < 50 && k < HID) ? postW1[k * 650 + (9 + s) * 50 + f] : 0.f; }
        break;
    case 10:
        if (idx < 13 * 256) { int f = q * 4 + j; Lt0[idx] = (f < 50 && k < HID) ? linW0[k * 50 + f] : 0.f; }
        break;
    case 11:
        if (idx < 13 * 256) { int f = q * 4 + j; Lt1[idx] = (f < 50 && k < HID) ? linW1[k * 50 + f] : 0.f; }
        break;
    }
}

// ---------- C = x@WL^T + b, P = x@WR^T; optional fused BN+ReLU on input load ----------
template <int F, int TF, int TFP, bool BN>
__global__ __launch_bounds__(256, 4) void k_gemm_CP(
    const float* __restrict__ x, const float* __restrict__ preWt,
    const float* __restrict__ b,
    const float* __restrict__ bnacc, const float* __restrict__ gam,
    const float* __restrict__ bet,
    float* __restrict__ C, float* __restrict__ P) {
    const int NODES = 16;
    __shared__ float xs[NODES * F];
    int tid = threadIdx.x;
    int base = blockIdx.x * NODES;
    for (int idx = tid; idx < NODES * F; idx += 256) {
        float v = x[(size_t)base * F + idx];
        if (BN) {
            int c = idx % F;
            float mu = bnacc[c] * (1.f / NN);
            float var = bnacc[64 + c] * (1.f / NN) - mu * mu;
            v = fmaxf(gam[c] * (v - mu) * rsqrtf(var + 1e-5f) + bet[c], 0.f);
        }
        xs[idx] = v;
    }
    __syncthreads();
    if (tid < TF) {
        float accC[NODES], accP[NODES];
#pragma unroll
        for (int n = 0; n < NODES; ++n) { accC[n] = 0.f; accP[n] = 0.f; }
        for (int f = 0; f < F; ++f) {
            float wl = preWt[f * TFP + tid];
            float wr = preWt[(F + f) * TFP + tid];
#pragma unroll
            for (int n = 0; n < NODES; ++n) {
                float xv = xs[n * F + f];
                accC[n] += xv * wl;
                accP[n] += xv * wr;
            }
        }
        float bb = b[tid];
        for (int n = 0; n < NODES; ++n) {
            C[((size_t)(base + n)) * TFP + tid] = accC[n] + bb;
            P[((size_t)(base + n)) * TFP + tid] = accP[n];
        }
    } else if (tid < TFP) {
        for (int n = 0; n < NODES; ++n) {
            C[((size_t)(base + n)) * TFP + tid] = 0.f;
            P[((size_t)(base + n)) * TFP + tid] = 0.f;
        }
    }
}

// ---------- fused conv: gather-stats (LDS) + post-GEMM + lin + BN-stats ----------
// 8 nodes/block, 8 waves (512 thr), one wave per node.
// TFPG: global C/P row stride; TFPL: LDS agg row stride.
template <int F, int TFPG, int TFPL, int EP, int SQ, int SQX, bool AF4, bool BNIN>
__global__ __launch_bounds__(512, 6) void k_conv(
    const float* __restrict__ xin, const float* __restrict__ C, const float* __restrict__ P,
    const int* __restrict__ offsets, const int* __restrict__ csr,
    const float* __restrict__ scal,
    const float* __restrict__ Wx, const float* __restrict__ Wid,
    const float* __restrict__ Wamp, const float* __restrict__ Watt,
    const float* __restrict__ postb, const float* __restrict__ Lt,
    const float* __restrict__ linb,
    const float* __restrict__ bn_in, const float* __restrict__ g_in,
    const float* __restrict__ b_in,
    float* __restrict__ hout, float* __restrict__ bn_out) {
    const int GP = TFPG / 4;
    const int GL = TFPL / 4;
    __shared__ __align__(16) float sAgg[8][5][TFPL];
    __shared__ __align__(16) float sY[8][52];
    int t = threadIdx.x, w = t >> 6, lane = t & 63;
    int i = blockIdx.x * 8 + w;
    int beg = offsets[i], end = offsets[i + 1];
    int d = end - beg;

    // ---- gather stats ----
    {
        int g = (EP == 1) ? lane : (lane % GL);
        int e = (EP == 1) ? 0 : (lane / GL);
        bool act = (EP == 1) ? (lane < GL) : (e < EP);
        f4 S = {0.f, 0.f, 0.f, 0.f}, S2 = {0.f, 0.f, 0.f, 0.f};
        f4 MN = {FLT_MAX, FLT_MAX, FLT_MAX, FLT_MAX};
        f4 MX = {-FLT_MAX, -FLT_MAX, -FLT_MAX, -FLT_MAX};
        const f4* __restrict__ Pv = (const f4*)P;
        if (act) {
            if (EP == 1) {
                int j = beg;
                for (; j + 4 <= end; j += 4) {
                    int s0 = csr[j], s1 = csr[j + 1], s2 = csr[j + 2], s3 = csr[j + 3];
                    f4 a = Pv[(size_t)s0 * GP + g];
                    f4 b = Pv[(size_t)s1 * GP + g];
                    f4 c = Pv[(size_t)s2 * GP + g];
                    f4 dd = Pv[(size_t)s3 * GP + g];
                    S += a; S2 += a * a; MN = f4_min(MN, a); MX = f4_max(MX, a);
                    S += b; S2 += b * b; MN = f4_min(MN, b); MX = f4_max(MX, b);
                    S += c; S2 += c * c; MN = f4_min(MN, c); MX = f4_max(MX, c);
                    S += dd; S2 += dd * dd; MN = f4_min(MN, dd); MX = f4_max(MX, dd);
                }
                for (; j < end; ++j) {
                    int s0 = csr[j];
                    f4 a = Pv[(size_t)s0 * GP + g];
                    S += a; S2 += a * a; MN = f4_min(MN, a); MX = f4_max(MX, a);
                }
            } else {
                int j = beg + e;
                for (; j + EP < end; j += 2 * EP) {
                    int s0 = csr[j], s1 = csr[j + EP];
                    f4 a = Pv[(size_t)s0 * GP + g];
                    f4 b = Pv[(size_t)s1 * GP + g];
                    S += a; S2 += a * a; MN = f4_min(MN, a); MX = f4_max(MX, a);
                    S += b; S2 += b * b; MN = f4_min(MN, b); MX = f4_max(MX, b);
                }
                if (j < end) {
                    int s0 = csr[j];
                    f4 a = Pv[(size_t)s0 * GP + g];
                    S += a; S2 += a * a; MN = f4_min(MN, a); MX = f4_max(MX, a);
                }
            }
        }
        if (EP == 3) {
            int g0 = lane % GL;
            S.x = sh3sum(S.x, g0, GL); S.y = sh3sum(S.y, g0, GL);
            S.z = sh3sum(S.z, g0, GL); S.w = sh3sum(S.w, g0, GL);
            S2.x = sh3sum(S2.x, g0, GL); S2.y = sh3sum(S2.y, g0, GL);
            S2.z = sh3sum(S2.z, g0, GL); S2.w = sh3sum(S2.w, g0, GL);
            MN.x = sh3min(MN.x, g0, GL); MN.y = sh3min(MN.y, g0, GL);
            MN.z = sh3min(MN.z, g0, GL); MN.w = sh3min(MN.w, g0, GL);
            MX.x = sh3max(MX.x, g0, GL); MX.y = sh3max(MX.y, g0, GL);
            MX.z = sh3max(MX.z, g0, GL); MX.w = sh3max(MX.w, g0, GL);
        }
        if (lane < GL) {
            f4 Cv = ((const f4*)C)[(size_t)i * GP + lane];
            float degf = (float)d;
            float rdegc = 1.0f / fmaxf(degf, 1.0f);
            f4 mean, sq, var, stdv, mnv, mxv;
            mean.x = (degf * Cv.x + S.x) * rdegc; mean.y = (degf * Cv.y + S.y) * rdegc;
            mean.z = (degf * Cv.z + S.z) * rdegc; mean.w = (degf * Cv.w + S.w) * rdegc;
            sq.x = degf * Cv.x * Cv.x + 2.f * Cv.x * S.x + S2.x;
            sq.y = degf * Cv.y * Cv.y + 2.f * Cv.y * S.y + S2.y;
            sq.z = degf * Cv.z * Cv.z + 2.f * Cv.z * S.z + S2.z;
            sq.w = degf * Cv.w * Cv.w + 2.f * Cv.w * S.w + S2.w;
            var.x = sq.x * rdegc - mean.x * mean.x; var.y = sq.y * rdegc - mean.y * mean.y;
            var.z = sq.z * rdegc - mean.z * mean.z; var.w = sq.w * rdegc - mean.w * mean.w;
            stdv.x = sqrtf(fmaxf(var.x, 0.f) + 1e-5f); stdv.y = sqrtf(fmaxf(var.y, 0.f) + 1e-5f);
            stdv.z = sqrtf(fmaxf(var.z, 0.f) + 1e-5f); stdv.w = sqrtf(fmaxf(var.w, 0.f) + 1e-5f);
            if (d > 0) {
                mnv.x = Cv.x + MN.x; mnv.y = Cv.y + MN.y; mnv.z = Cv.z + MN.z; mnv.w = Cv.w + MN.w;
                mxv.x = Cv.x + MX.x; mxv.y = Cv.y + MX.y; mxv.z = Cv.z + MX.z; mxv.w = Cv.w + MX.w;
            } else {
                mnv = (f4){0.f, 0.f, 0.f, 0.f}; mxv = mnv;
            }
            ((f4*)&sAgg[w][0][0])[lane] = mean;
            ((f4*)&sAgg[w][1][0])[lane] = mnv;
            ((f4*)&sAgg[w][2][0])[lane] = mxv;
            ((f4*)&sAgg[w][3][0])[lane] = stdv;
        }
    }
    // ---- x load (with optional BN+ReLU) ----
    if (BNIN) {
        if (lane < F) {
            float hv = xin[(size_t)i * F + lane];
            float mu = bn_in[lane] * (1.f / NN);
            float var = bn_in[64 + lane] * (1.f / NN) - mu * mu;
            sAgg[w][4][lane] = fmaxf(g_in[lane] * (hv - mu) * rsqrtf(var + 1e-5f) + b_in[lane], 0.f);
        } else if (lane < SQX * 4) {
            sAgg[w][4][lane] = 0.f;
        }
    } else {
        if (lane < F) sAgg[w][4][lane] = xin[(size_t)i * F + lane];
        else if (lane < SQX * 4) sAgg[w][4][lane] = 0.f;
    }
    float amp = logf(fmaxf((float)d, 1.f) + 1.f) / scal[0];
    float ia = 1.0f / amp;
    __syncthreads();  // lockstep waves for shared W stream

    // ---- post-GEMM ----
    int kk = (lane < HID) ? lane : (HID - 1);
    int tw = kk / FO;
    const f4* __restrict__ Wxv = (const f4*)Wx;
    const f4* __restrict__ Wiv = (const f4*)Wid;
    const f4* __restrict__ Wav = (const f4*)Wamp;
    const f4* __restrict__ Wtv = (const f4*)Watt;
    float y0 = 0.f, y1 = 0.f, y2 = 0.f;
#pragma unroll
    for (int q = 0; q < SQX; ++q) {
        f4 wv = Wxv[q * 64 + lane];
        f4 a = *(const f4*)(&sAgg[w][4][4 * q]);
        acc4(y0, wv, a.x, a.y, a.z, a.w);
    }
#pragma unroll
    for (int s = 0; s < 4; ++s) {
        const float* __restrict__ A = &sAgg[w][s][tw * F];
#pragma unroll 4
        for (int q = 0; q < SQ; ++q) {
            f4 wi = Wiv[(s * SQ + q) * 64 + lane];
            f4 wa = Wav[(s * SQ + q) * 64 + lane];
            f4 wt = Wtv[(s * SQ + q) * 64 + lane];
            float a0, a1, a2, a3;
            if constexpr (AF4) {
                f4 av = *(const f4*)(A + 4 * q);
                a0 = av.x; a1 = av.y; a2 = av.z; a3 = av.w;
            } else {
                f2 u = *(const f2*)(A + 4 * q);
                f2 v = *(const f2*)(A + 4 * q + 2);
                a0 = u.x; a1 = u.y; a2 = v.x; a3 = v.y;
            }
            acc4(y0, wi, a0, a1, a2, a3);
            acc4(y1, wa, a0, a1, a2, a3);
            acc4(y2, wt, a0, a1, a2, a3);
        }
    }
    float y = postb[kk] + y0 + amp * y1 + ia * y2;
    if (lane < HID) sY[w][lane] = y;
    else if (lane < 52) sY[w][lane] = 0.f;
    // wave-private LDS: no barrier needed

    // ---- lin ----
    const f4* __restrict__ Lv = (const f4*)Lt;
    float o = linb[kk];
#pragma unroll
    for (int q = 0; q < 13; ++q) {
        f4 lv = Lv[q * 64 + lane];
        f4 sv = *(const f4*)(&sY[w][4 * q]);
        acc4(o, lv, sv.x, sv.y, sv.z, sv.w);
    }
    if (lane < HID) hout[(size_t)i * HID + lane] = o;

    // ---- BN partial stats (block reduce + atomics) ----
    float ov = (lane < HID) ? o : 0.f;
    sAgg[w][0][lane] = ov;
    sAgg[w][1][lane] = ov * ov;
    __syncthreads();
    if (t < 64 && lane < HID) {
        float s = 0.f, s2 = 0.f;
#pragma unroll
        for (int w2 = 0; w2 < 8; ++w2) {
            s += sAgg[w2][0][lane];
            s2 += sAgg[w2][1][lane];
        }
        atomicAdd(&bn_out[lane], s);
        atomicAdd(&bn_out[64 + lane], s2);
    }
}

// ---------- fused bounds + BN+ReLU + pooling + head MLP ----------
__global__ void k_head(const float* __restrict__ h, const int* __restrict__ batch,
                       const float* __restrict__ bnacc, const float* __restrict__ gam,
                       const float* __restrict__ bet,
                       const float* __restrict__ W1, const float* __restrict__ b1,
                       const float* __restrict__ W2, const float* __restrict__ b2,
                       const float* __restrict__ W3, const float* __restrict__ b3,
                       float* __restrict__ out) {
    __shared__ float sp[HID], h1[50], h2[25];
    __shared__ int sbound[2];
    int g = blockIdx.x, tid = threadIdx.x;
    if (tid < 2) {
        int target = g + tid;
        int lo = 0, hi = NN;
        while (lo < hi) {
            int mid = (lo + hi) >> 1;
            if (batch[mid] < target) lo = mid + 1; else hi = mid;
        }
        sbound[tid] = lo;
    }
    __syncthreads();
    int beg = sbound[0], end = sbound[1];
    if (tid < HID) {
        float mu = bnacc[tid] * (1.f / NN);
        float var = bnacc[64 + tid] * (1.f / NN) - mu * mu;
        float sc = gam[tid] * rsqrtf(var + 1e-5f);
        float sh = bet[tid] - mu * sc;
        float s0 = 0.f, s1 = 0.f, s2 = 0.f, s3 = 0.f;
        int n = beg;
        for (; n + 4 <= end; n += 4) {
            s0 += fmaxf(fmaf(h[(size_t)n * HID + tid], sc, sh), 0.f);
            s1 += fmaxf(fmaf(h[(size_t)(n + 1) * HID + tid], sc, sh), 0.f);
            s2 += fmaxf(fmaf(h[(size_t)(n + 2) * HID + tid], sc, sh), 0.f);
            s3 += fmaxf(fmaf(h[(size_t)(n + 3) * HID + tid], sc, sh), 0.f);
        }
        for (; n < end; ++n) s0 += fmaxf(fmaf(h[(size_t)n * HID + tid], sc, sh), 0.f);
        sp[tid] = (s0 + s1 + s2 + s3) / fmaxf((float)(end - beg), 1.0f);
    }
    __syncthreads();
    if (tid < 50) {
        float a = b1[tid];
        for (int k = 0; k < HID; ++k) a += W1[tid * HID + k] * sp[k];
        h1[tid] = fmaxf(a, 0.f);
    }
    __syncthreads();
    if (tid < 25) {
        float a = b2[tid];
        for (int k = 0; k < 50; ++k) a += W2[tid * 50 + k] * h1[k];
        h2[tid] = fmaxf(a, 0.f);
    }
    __syncthreads();
    if (tid == 0) {
        float a = b3[0];
        for (int k = 0; k < 25; ++k) a += W3[k] * h2[k];
        out[g] = a;
    }
}

extern "C" void kernel_launch(void* const* d_in, const int* in_sizes, int n_in,
                              void* d_out, int out_size, void* d_ws, size_t ws_size,
                              hipStream_t stream) {
    const float* x      = (const float*)d_in[0];
    const int*   ei     = (const int*)d_in[1];
    const int*   batch  = (const int*)d_in[2];
    const float* preW0  = (const float*)d_in[3];
    const float* preb0  = (const float*)d_in[4];
    const float* postW0 = (const float*)d_in[5];
    const float* postb0 = (const float*)d_in[6];
    const float* linW0  = (const float*)d_in[7];
    const float* linb0  = (const float*)d_in[8];
    const float* gamma0 = (const float*)d_in[9];
    const float* beta0  = (const float*)d_in[10];
    const float* preW1  = (const float*)d_in[11];
    const float* preb1  = (const float*)d_in[12];
    const float* postW1 = (const float*)d_in[13];
    const float* postb1 = (const float*)d_in[14];
    const float* linW1  = (const float*)d_in[15];
    const float* linb1  = (const float*)d_in[16];
    const float* gamma1 = (const float*)d_in[17];
    const float* beta1  = (const float*)d_in[18];
    const float* mW1    = (const float*)d_in[19];
    const float* mb1    = (const float*)d_in[20];
    const float* mW2    = (const float*)d_in[21];
    const float* mb2    = (const float*)d_in[22];
    const float* mW3    = (const float*)d_in[23];
    const float* mb3    = (const float*)d_in[24];
    float* out = (float*)d_out;
    (void)in_sizes; (void)n_in; (void)out_size; (void)ws_size;

    char* ws = (char*)d_ws;
    size_t off = 0;
    auto alloc = [&](size_t bytes) -> void* {
        void* p = ws + off;
        off += (bytes + 255) & ~(size_t)255;
        return p;
    };
    // zero-region (one memset): deg, cursor, bnacc0, bnacc1
    int*   deg     = (int*)alloc((size_t)NN * 4);
    int*   cursor  = (int*)alloc((size_t)NN * 4);
    float* bnacc0  = (float*)alloc(128 * 4);
    float* bnacc1  = (float*)alloc(128 * 4);
    size_t zero_bytes = off;
    int*   offsets = (int*)alloc((size_t)(NN + 1) * 4);
    int*   csr_src = (int*)alloc((size_t)EE * 4);
    float* scal    = (float*)alloc(64);
    float* preWt0  = (float*)alloc((size_t)32 * 80 * 4);
    float* preWt1  = (float*)alloc((size_t)100 * 256 * 4);
    float* Wx0     = (float*)alloc((size_t)4 * 256 * 4);
    float* Wid0    = (float*)alloc((size_t)16 * 256 * 4);
    float* Wamp0   = (float*)alloc((size_t)16 * 256 * 4);
    float* Watt0   = (float*)alloc((size_t)16 * 256 * 4);
    float* Wx1     = (float*)alloc((size_t)13 * 256 * 4);
    float* Wid1    = (float*)alloc((size_t)52 * 256 * 4);
    float* Wamp1   = (float*)alloc((size_t)52 * 256 * 4);
    float* Watt1   = (float*)alloc((size_t)52 * 256 * 4);
    float* Lt0     = (float*)alloc((size_t)13 * 256 * 4);
    float* Lt1     = (float*)alloc((size_t)13 * 256 * 4);
    float* Cbuf    = (float*)alloc((size_t)NN * 256 * 4);
    float* Pbuf    = (float*)alloc((size_t)NN * 256 * 4);
    float* h1buf   = (float*)alloc((size_t)NN * HID * 4);
    float* h2buf   = (float*)alloc((size_t)NN * HID * 4);

    const int* src = ei;
    const int* dst = ei + EE;

    hipMemsetAsync(ws, 0, zero_bytes, stream);

    k_pack<<<dim3(100, 12), 256, 0, stream>>>(preW0, preW1, postW0, postW1, linW0, linW1,
                                              preWt0, preWt1, Wx0, Wid0, Wamp0, Watt0,
                                              Wx1, Wid1, Wamp1, Watt1, Lt0, Lt1);
    k_deg<<<EE / 256, 256, 0, stream>>>(dst, deg);
    k_scan<<<1, 1024, 0, stream>>>(deg, offsets, scal);
    k_fill<<<EE / 256, 256, 0, stream>>>(src, dst, offsets, cursor, csr_src);

    // ---- conv0 (F=16, TFPG=TFPL=80, EP=3) ----
    k_gemm_CP<INDIM, 80, 80, false><<<NN / 16, 256, 0, stream>>>(
        x, preWt0, preb0, nullptr, nullptr, nullptr, Cbuf, Pbuf);
    k_conv<INDIM, 80, 80, 3, 4, 4, true, false><<<NN / 8, 512, 0, stream>>>(
        x, Cbuf, Pbuf, offsets, csr_src, scal, Wx0, Wid0, Wamp0, Watt0, postb0, Lt0, linb0,
        nullptr, nullptr, nullptr, h1buf, bnacc0);

    // ---- conv1 (F=50, TFPG=256, TFPL=252, EP=1); BN0+ReLU fused into loads ----
    k_gemm_CP<HID, 250, 256, true><<<NN / 16, 256, 0, stream>>>(
        h1buf, preWt1, preb1, bnacc0, gamma0, beta0, Cbuf, Pbuf);
    k_conv<HID, 256, 252, 1, 13, 13, false, true><<<NN / 8, 512, 0, stream>>>(
        h1buf, Cbuf, Pbuf, offsets, csr_src, scal, Wx1, Wid1, Wamp1, Watt1, postb1, Lt1, linb1,
        bnacc0, gamma0, beta0, h2buf, bnacc1);

    // ---- BN1+ReLU fused into pooling + head ----
    k_head<<<NGROUPS, 64, 0, stream>>>(h2buf, batch, bnacc1, gamma1, beta1,
                                       mW1, mb1, mW2, mb2, mW3, mb3, out);
}

// Round 7
// 325.190 us; speedup vs baseline: 1.1827x; 1.0600x over previous
//
#include <hip/hip_runtime.h>
#include <math.h>
#include <float.h>

#define NN 20000
#define EE 320000
#define INDIM 16
#define HID 50
#define TW 5
#define FO 10
#define NGROUPS 64

typedef float f4 __attribute__((ext_vector_type(4)));
typedef float f2 __attribute__((ext_vector_type(2)));

__device__ inline f4 f4_min(f4 a, f4 b) {
    f4 r; r.x = fminf(a.x, b.x); r.y = fminf(a.y, b.y);
    r.z = fminf(a.z, b.z); r.w = fminf(a.w, b.w); return r;
}
__device__ inline f4 f4_max(f4 a, f4 b) {
    f4 r; r.x = fmaxf(a.x, b.x); r.y = fmaxf(a.y, b.y);
    r.z = fmaxf(a.z, b.z); r.w = fmaxf(a.w, b.w); return r;
}
__device__ inline float sh3sum(float v, int g0, int G_) {
    return v + __shfl(v, g0 + G_, 64) + __shfl(v, g0 + 2 * G_, 64);
}
__device__ inline float sh3min(float v, int g0, int G_) {
    return fminf(fminf(v, __shfl(v, g0 + G_, 64)), __shfl(v, g0 + 2 * G_, 64));
}
__device__ inline float sh3max(float v, int g0, int G_) {
    return fmaxf(fmaxf(v, __shfl(v, g0 + G_, 64)), __shfl(v, g0 + 2 * G_, 64));
}
__device__ inline void acc4(float& acc, f4 w, float a0, float a1, float a2, float a3) {
    acc += w.x * a0; acc += w.y * a1; acc += w.z * a2; acc += w.w * a3;
}

// ---------- CSR build ----------
__global__ void k_deg(const int* __restrict__ dst, int* __restrict__ deg) {
    int e = blockIdx.x * 256 + threadIdx.x;
    if (e < EE) atomicAdd(&deg[dst[e]], 1);
}

__global__ void k_scan(const int* __restrict__ deg, int* __restrict__ offsets,
                       float* __restrict__ scal) {
    __shared__ int part[1024];
    __shared__ float fred[1024];
    const int CH = 20;
    int tid = threadIdx.x;
    int base = tid * CH;
    int loc[CH];
    int s = 0; float fs = 0.f;
    for (int c = 0; c < CH; ++c) {
        int idx = base + c;
        int v = (idx < NN) ? deg[idx] : 0;
        loc[c] = s; s += v;
        if (idx < NN) fs += logf((float)v + 1.0f);
    }
    part[tid] = s; fred[tid] = fs; __syncthreads();
    for (int off = 1; off < 1024; off <<= 1) {
        int v = (tid >= off) ? part[tid - off] : 0;
        __syncthreads();
        part[tid] += v;
        __syncthreads();
    }
    int pre = (tid > 0) ? part[tid - 1] : 0;
    for (int c = 0; c < CH; ++c) {
        int idx = base + c;
        if (idx < NN) offsets[idx] = pre + loc[c];
    }
    if (tid == 0) offsets[NN] = part[1023];
    for (int off = 512; off > 0; off >>= 1) {
        if (tid < off) fred[tid] += fred[tid + off];
        __syncthreads();
    }
    if (tid == 0) scal[0] = fred[0] / (float)NN;
}

__global__ void k_fill(const int* __restrict__ src, const int* __restrict__ dst,
                       const int* __restrict__ offsets, int* __restrict__ cursor,
                       int* __restrict__ csr_src) {
    int e = blockIdx.x * 256 + threadIdx.x;
    if (e < EE) {
        int d = dst[e];
        int pos = offsets[d] + atomicAdd(&cursor[d], 1);
        csr_src[pos] = src[e];
    }
}

// ---------- pack all weight layouts in one kernel ----------
__global__ void k_pack(const float* __restrict__ preW0, const float* __restrict__ preW1,
                       const float* __restrict__ postW0, const float* __restrict__ postW1,
                       const float* __restrict__ linW0, const float* __restrict__ linW1,
                       float* __restrict__ preWt0, float* __restrict__ preWt1,
                       float* __restrict__ Wx0, float* __restrict__ Wid0,
                       float* __restrict__ Wamp0, float* __restrict__ Watt0,
                       float* __restrict__ Wx1, float* __restrict__ Wid1,
                       float* __restrict__ Wamp1, float* __restrict__ Watt1,
                       float* __restrict__ Lt0, float* __restrict__ Lt1) {
    int idx = blockIdx.x * 256 + threadIdx.x;
    int job = blockIdx.y;
    int q = idx >> 8, k = (idx >> 2) & 63, j = idx & 3;
    switch (job) {
    case 0:
        if (idx < 32 * 80) { int c = idx / 80, r = idx % 80; preWt0[idx] = preW0[r * 32 + c]; }
        break;
    case 1:
        if (idx < 100 * 256) { int c = idx / 256, r = idx % 256; preWt1[idx] = (r < 250) ? preW1[r * 100 + c] : 0.f; }
        break;
    case 2:
        if (idx < 4 * 256) { int f = q * 4 + j; Wx0[idx] = (k < HID) ? postW0[k * 208 + f] : 0.f; }
        break;
    case 3:
        if (idx < 16 * 256) { int s = q / 4, f = (q % 4) * 4 + j; Wid0[idx] = (k < HID) ? postW0[k * 208 + (1 + s) * 16 + f] : 0.f; }
        break;
    case 4:
        if (idx < 16 * 256) { int s = q / 4, f = (q % 4) * 4 + j; Wamp0[idx] = (k < HID) ? postW0[k * 208 + (5 + s) * 16 + f] : 0.f; }
        break;
    case 5:
        if (idx < 16 * 256) { int s = q / 4, f = (q % 4) * 4 + j; Watt0[idx] = (k < HID) ? postW0[k * 208 + (9 + s) * 16 + f] : 0.f; }
        break;
    case 6:
        if (idx < 13 * 256) { int f = q * 4 + j; Wx1[idx] = (f < 50 && k < HID) ? postW1[k * 650 + f] : 0.f; }
        break;
    case 7:
        if (idx < 52 * 256) { int s = q / 13, f = (q % 13) * 4 + j; Wid1[idx] = (f < 50 && k < HID) ? postW1[k * 650 + (1 + s) * 50 + f] : 0.f; }
        break;
    case 8:
        if (idx < 52 * 256) { int s = q / 13, f = (q % 13) * 4 + j; Wamp1[idx] = (f < 50 && k < HID) ? postW1[k * 650 + (5 + s) * 50 + f] : 0.f; }
        break;
    case 9:
        if (idx < 52 * 256) { int s = q / 13, f = (q % 13) * 4 + j; Watt1[idx] = (f < 50 && k < HID) ? postW1[k * 650 + (9 + s) * 50 + f] : 0.f; }
        break;
    case 10:
        if (idx < 13 * 256) { int f = q * 4 + j; Lt0[idx] = (f < 50 && k < HID) ? linW0[k * 50 + f] : 0.f; }
        break;
    case 11:
        if (idx < 13 * 256) { int f = q * 4 + j; Lt1[idx] = (f < 50 && k < HID) ? linW1[k * 50 + f] : 0.f; }
        break;
    }
}

// ---------- C = x@WL^T + b, P = x@WR^T; optional fused BN+ReLU on input load ----------
template <int F, int TF, int TFP, bool BN>
__global__ __launch_bounds__(256, 4) void k_gemm_CP(
    const float* __restrict__ x, const float* __restrict__ preWt,
    const float* __restrict__ b,
    const float* __restrict__ bnacc, const float* __restrict__ gam,
    const float* __restrict__ bet,
    float* __restrict__ C, float* __restrict__ P) {
    const int NODES = 16;
    __shared__ float xs[NODES * F];
    int tid = threadIdx.x;
    int base = blockIdx.x * NODES;
    for (int idx = tid; idx < NODES * F; idx += 256) {
        float v = x[(size_t)base * F + idx];
        if (BN) {
            int c = idx % F;
            float mu = bnacc[c] * (1.f / NN);
            float var = bnacc[64 + c] * (1.f / NN) - mu * mu;
            v = fmaxf(gam[c] * (v - mu) * rsqrtf(var + 1e-5f) + bet[c], 0.f);
        }
        xs[idx] = v;
    }
    __syncthreads();
    if (tid < TF) {
        float accC[NODES], accP[NODES];
#pragma unroll
        for (int n = 0; n < NODES; ++n) { accC[n] = 0.f; accP[n] = 0.f; }
        for (int f = 0; f < F; ++f) {
            float wl = preWt[f * TFP + tid];
            float wr = preWt[(F + f) * TFP + tid];
#pragma unroll
            for (int n = 0; n < NODES; ++n) {
                float xv = xs[n * F + f];
                accC[n] += xv * wl;
                accP[n] += xv * wr;
            }
        }
        float bb = b[tid];
        for (int n = 0; n < NODES; ++n) {
            C[((size_t)(base + n)) * TFP + tid] = accC[n] + bb;
            P[((size_t)(base + n)) * TFP + tid] = accP[n];
        }
    } else if (tid < TFP) {
        for (int n = 0; n < NODES; ++n) {
            C[((size_t)(base + n)) * TFP + tid] = 0.f;
            P[((size_t)(base + n)) * TFP + tid] = 0.f;
        }
    }
}

// ---------- fused conv: gather-stats (LDS) + post-GEMM (R=2) + lin + BN-stats ----------
// 8 nodes/block, 4 waves (256 thr); wave w owns nodes {2w, 2w+1}.
template <int F, int TFPG, int TFPL, int EP, int SQ, int SQX, bool AF4, bool BNIN>
__global__ __launch_bounds__(256, 4) void k_conv(
    const float* __restrict__ xin, const float* __restrict__ C, const float* __restrict__ P,
    const int* __restrict__ offsets, const int* __restrict__ csr,
    const float* __restrict__ scal,
    const float* __restrict__ Wx, const float* __restrict__ Wid,
    const float* __restrict__ Wamp, const float* __restrict__ Watt,
    const float* __restrict__ postb, const float* __restrict__ Lt,
    const float* __restrict__ linb,
    const float* __restrict__ bn_in, const float* __restrict__ g_in,
    const float* __restrict__ b_in,
    float* __restrict__ hout, float* __restrict__ bn_out) {
    const int GP = TFPG / 4;
    const int GL = TFPL / 4;
    __shared__ __align__(16) float sAgg[8][4][TFPL];
    __shared__ __align__(16) float sX[8][64];
    __shared__ __align__(16) float sY[8][52];
    __shared__ float sBN[4][2][64];
    int t = threadIdx.x, w = t >> 6, lane = t & 63;
    int ibase = blockIdx.x * 8 + 2 * w;
    float ampv[2], iav[2];

    for (int nn = 0; nn < 2; ++nn) {
        int nd = 2 * w + nn;
        int i = ibase + nn;
        int beg = offsets[i], end = offsets[i + 1];
        int d = end - beg;
        int g = (EP == 1) ? lane : (lane % GL);
        int e = (EP == 1) ? 0 : (lane / GL);
        bool act = (EP == 1) ? (lane < GL) : (e < EP);
        f4 S = {0.f, 0.f, 0.f, 0.f}, S2 = {0.f, 0.f, 0.f, 0.f};
        f4 MN = {FLT_MAX, FLT_MAX, FLT_MAX, FLT_MAX};
        f4 MX = {-FLT_MAX, -FLT_MAX, -FLT_MAX, -FLT_MAX};
        const f4* __restrict__ Pv = (const f4*)P;
        if (act) {
            if (EP == 1) {
                int j = beg;
                for (; j + 4 <= end; j += 4) {
                    int s0 = csr[j], s1 = csr[j + 1], s2 = csr[j + 2], s3 = csr[j + 3];
                    f4 a = Pv[(size_t)s0 * GP + g];
                    f4 b = Pv[(size_t)s1 * GP + g];
                    f4 c = Pv[(size_t)s2 * GP + g];
                    f4 dd = Pv[(size_t)s3 * GP + g];
                    S += a; S2 += a * a; MN = f4_min(MN, a); MX = f4_max(MX, a);
                    S += b; S2 += b * b; MN = f4_min(MN, b); MX = f4_max(MX, b);
                    S += c; S2 += c * c; MN = f4_min(MN, c); MX = f4_max(MX, c);
                    S += dd; S2 += dd * dd; MN = f4_min(MN, dd); MX = f4_max(MX, dd);
                }
                for (; j < end; ++j) {
                    int s0 = csr[j];
                    f4 a = Pv[(size_t)s0 * GP + g];
                    S += a; S2 += a * a; MN = f4_min(MN, a); MX = f4_max(MX, a);
                }
            } else {
                int j = beg + e;
                for (; j + EP < end; j += 2 * EP) {
                    int s0 = csr[j], s1 = csr[j + EP];
                    f4 a = Pv[(size_t)s0 * GP + g];
                    f4 b = Pv[(size_t)s1 * GP + g];
                    S += a; S2 += a * a; MN = f4_min(MN, a); MX = f4_max(MX, a);
                    S += b; S2 += b * b; MN = f4_min(MN, b); MX = f4_max(MX, b);
                }
                if (j < end) {
                    int s0 = csr[j];
                    f4 a = Pv[(size_t)s0 * GP + g];
                    S += a; S2 += a * a; MN = f4_min(MN, a); MX = f4_max(MX, a);
                }
            }
        }
        if (EP == 3) {
            int g0 = lane % GL;
            S.x = sh3sum(S.x, g0, GL); S.y = sh3sum(S.y, g0, GL);
            S.z = sh3sum(S.z, g0, GL); S.w = sh3sum(S.w, g0, GL);
            S2.x = sh3sum(S2.x, g0, GL); S2.y = sh3sum(S2.y, g0, GL);
            S2.z = sh3sum(S2.z, g0, GL); S2.w = sh3sum(S2.w, g0, GL);
            MN.x = sh3min(MN.x, g0, GL); MN.y = sh3min(MN.y, g0, GL);
            MN.z = sh3min(MN.z, g0, GL); MN.w = sh3min(MN.w, g0, GL);
            MX.x = sh3max(MX.x, g0, GL); MX.y = sh3max(MX.y, g0, GL);
            MX.z = sh3max(MX.z, g0, GL); MX.w = sh3max(MX.w, g0, GL);
        }
        if (lane < GL) {
            f4 Cv = ((const f4*)C)[(size_t)i * GP + lane];
            float degf = (float)d;
            float rdegc = 1.0f / fmaxf(degf, 1.0f);
            f4 mean, sq, var, stdv, mnv, mxv;
            mean.x = (degf * Cv.x + S.x) * rdegc; mean.y = (degf * Cv.y + S.y) * rdegc;
            mean.z = (degf * Cv.z + S.z) * rdegc; mean.w = (degf * Cv.w + S.w) * rdegc;
            sq.x = degf * Cv.x * Cv.x + 2.f * Cv.x * S.x + S2.x;
            sq.y = degf * Cv.y * Cv.y + 2.f * Cv.y * S.y + S2.y;
            sq.z = degf * Cv.z * Cv.z + 2.f * Cv.z * S.z + S2.z;
            sq.w = degf * Cv.w * Cv.w + 2.f * Cv.w * S.w + S2.w;
            var.x = sq.x * rdegc - mean.x * mean.x; var.y = sq.y * rdegc - mean.y * mean.y;
            var.z = sq.z * rdegc - mean.z * mean.z; var.w = sq.w * rdegc - mean.w * mean.w;
            stdv.x = sqrtf(fmaxf(var.x, 0.f) + 1e-5f); stdv.y = sqrtf(fmaxf(var.y, 0.f) + 1e-5f);
            stdv.z = sqrtf(fmaxf(var.z, 0.f) + 1e-5f); stdv.w = sqrtf(fmaxf(var.w, 0.f) + 1e-5f);
            if (d > 0) {
                mnv.x = Cv.x + MN.x; mnv.y = Cv.y + MN.y; mnv.z = Cv.z + MN.z; mnv.w = Cv.w + MN.w;
                mxv.x = Cv.x + MX.x; mxv.y = Cv.y + MX.y; mxv.z = Cv.z + MX.z; mxv.w = Cv.w + MX.w;
            } else {
                mnv = (f4){0.f, 0.f, 0.f, 0.f}; mxv = mnv;
            }
            ((f4*)&sAgg[nd][0][0])[lane] = mean;
            ((f4*)&sAgg[nd][1][0])[lane] = mnv;
            ((f4*)&sAgg[nd][2][0])[lane] = mxv;
            ((f4*)&sAgg[nd][3][0])[lane] = stdv;
        }
        if (BNIN) {
            if (lane < F) {
                float hv = xin[(size_t)i * F + lane];
                float mu = bn_in[lane] * (1.f / NN);
                float var = bn_in[64 + lane] * (1.f / NN) - mu * mu;
                sX[nd][lane] = fmaxf(g_in[lane] * (hv - mu) * rsqrtf(var + 1e-5f) + b_in[lane], 0.f);
            } else if (lane < SQX * 4) {
                sX[nd][lane] = 0.f;
            }
        } else {
            if (lane < F) sX[nd][lane] = xin[(size_t)i * F + lane];
            else if (lane < SQX * 4) sX[nd][lane] = 0.f;
        }
        float amp = logf(fmaxf((float)d, 1.f) + 1.f) / scal[0];
        ampv[nn] = amp; iav[nn] = 1.0f / amp;
    }
    __syncthreads();  // lockstep waves for shared W stream

    // ---- post-GEMM, R=2 ----
    int nd0 = 2 * w, nd1 = 2 * w + 1;
    int i0 = ibase, i1 = ibase + 1;
    int kk = (lane < HID) ? lane : (HID - 1);
    int tw = kk / FO;
    const f4* __restrict__ Wxv = (const f4*)Wx;
    const f4* __restrict__ Wiv = (const f4*)Wid;
    const f4* __restrict__ Wav = (const f4*)Wamp;
    const f4* __restrict__ Wtv = (const f4*)Watt;
    float y0a = 0.f, y1a = 0.f, y2a = 0.f, y0b = 0.f, y1b = 0.f, y2b = 0.f;
#pragma unroll
    for (int q = 0; q < SQX; ++q) {
        f4 wv = Wxv[q * 64 + lane];
        f4 a0 = *(const f4*)(&sX[nd0][4 * q]);
        f4 a1 = *(const f4*)(&sX[nd1][4 * q]);
        acc4(y0a, wv, a0.x, a0.y, a0.z, a0.w);
        acc4(y0b, wv, a1.x, a1.y, a1.z, a1.w);
    }
#pragma unroll
    for (int s = 0; s < 4; ++s) {
        const float* __restrict__ A0 = &sAgg[nd0][s][tw * F];
        const float* __restrict__ A1 = &sAgg[nd1][s][tw * F];
#pragma unroll 4
        for (int q = 0; q < SQ; ++q) {
            f4 wi = Wiv[(s * SQ + q) * 64 + lane];
            f4 wa = Wav[(s * SQ + q) * 64 + lane];
            f4 wt = Wtv[(s * SQ + q) * 64 + lane];
            float a00, a01, a02, a03, a10, a11, a12, a13;
            if constexpr (AF4) {
                f4 v0 = *(const f4*)(A0 + 4 * q);
                f4 v1 = *(const f4*)(A1 + 4 * q);
                a00 = v0.x; a01 = v0.y; a02 = v0.z; a03 = v0.w;
                a10 = v1.x; a11 = v1.y; a12 = v1.z; a13 = v1.w;
            } else {
                f2 p0 = *(const f2*)(A0 + 4 * q);
                f2 p1 = *(const f2*)(A0 + 4 * q + 2);
                f2 q0 = *(const f2*)(A1 + 4 * q);
                f2 q1 = *(const f2*)(A1 + 4 * q + 2);
                a00 = p0.x; a01 = p0.y; a02 = p1.x; a03 = p1.y;
                a10 = q0.x; a11 = q0.y; a12 = q1.x; a13 = q1.y;
            }
            acc4(y0a, wi, a00, a01, a02, a03);
            acc4(y1a, wa, a00, a01, a02, a03);
            acc4(y2a, wt, a00, a01, a02, a03);
            acc4(y0b, wi, a10, a11, a12, a13);
            acc4(y1b, wa, a10, a11, a12, a13);
            acc4(y2b, wt, a10, a11, a12, a13);
        }
    }
    float pb = postb[kk];
    float ya = pb + y0a + ampv[0] * y1a + iav[0] * y2a;
    float yb = pb + y0b + ampv[1] * y1b + iav[1] * y2b;
    if (lane < HID) { sY[nd0][lane] = ya; sY[nd1][lane] = yb; }
    else if (lane < 52) { sY[nd0][lane] = 0.f; sY[nd1][lane] = 0.f; }
    // wave-private sY: no barrier needed

    // ---- lin ----
    const f4* __restrict__ Lv = (const f4*)Lt;
    float lb = linb[kk];
    float oa = lb, ob = lb;
#pragma unroll
    for (int q = 0; q < 13; ++q) {
        f4 lv = Lv[q * 64 + lane];
        f4 s0 = *(const f4*)(&sY[nd0][4 * q]);
        f4 s1 = *(const f4*)(&sY[nd1][4 * q]);
        acc4(oa, lv, s0.x, s0.y, s0.z, s0.w);
        acc4(ob, lv, s1.x, s1.y, s1.z, s1.w);
    }
    if (lane < HID) {
        hout[(size_t)i0 * HID + lane] = oa;
        hout[(size_t)i1 * HID + lane] = ob;
    }

    // ---- BN partial stats ----
    float sv = 0.f, sv2 = 0.f;
    if (lane < HID) { sv = oa + ob; sv2 = oa * oa + ob * ob; }
    sBN[w][0][lane] = sv;
    sBN[w][1][lane] = sv2;
    __syncthreads();
    if (t < 64 && lane < HID) {
        float s = sBN[0][0][lane] + sBN[1][0][lane] + sBN[2][0][lane] + sBN[3][0][lane];
        float s2 = sBN[0][1][lane] + sBN[1][1][lane] + sBN[2][1][lane] + sBN[3][1][lane];
        atomicAdd(&bn_out[lane], s);
        atomicAdd(&bn_out[64 + lane], s2);
    }
}

// ---------- fused bounds + BN+ReLU + pooling + head MLP ----------
__global__ void k_head(const float* __restrict__ h, const int* __restrict__ batch,
                       const float* __restrict__ bnacc, const float* __restrict__ gam,
                       const float* __restrict__ bet,
                       const float* __restrict__ W1, const float* __restrict__ b1,
                       const float* __restrict__ W2, const float* __restrict__ b2,
                       const float* __restrict__ W3, const float* __restrict__ b3,
                       float* __restrict__ out) {
    __shared__ float sp[HID], h1[50], h2[25];
    __shared__ int sbound[2];
    int g = blockIdx.x, tid = threadIdx.x;
    if (tid < 2) {
        int target = g + tid;
        int lo = 0, hi = NN;
        while (lo < hi) {
            int mid = (lo + hi) >> 1;
            if (batch[mid] < target) lo = mid + 1; else hi = mid;
        }
        sbound[tid] = lo;
    }
    __syncthreads();
    int beg = sbound[0], end = sbound[1];
    if (tid < HID) {
        float mu = bnacc[tid] * (1.f / NN);
        float var = bnacc[64 + tid] * (1.f / NN) - mu * mu;
        float sc = gam[tid] * rsqrtf(var + 1e-5f);
        float sh = bet[tid] - mu * sc;
        float s0 = 0.f, s1 = 0.f, s2 = 0.f, s3 = 0.f;
        int n = beg;
        for (; n + 4 <= end; n += 4) {
            s0 += fmaxf(fmaf(h[(size_t)n * HID + tid], sc, sh), 0.f);
            s1 += fmaxf(fmaf(h[(size_t)(n + 1) * HID + tid], sc, sh), 0.f);
            s2 += fmaxf(fmaf(h[(size_t)(n + 2) * HID + tid], sc, sh), 0.f);
            s3 += fmaxf(fmaf(h[(size_t)(n + 3) * HID + tid], sc, sh), 0.f);
        }
        for (; n < end; ++n) s0 += fmaxf(fmaf(h[(size_t)n * HID + tid], sc, sh), 0.f);
        sp[tid] = (s0 + s1 + s2 + s3) / fmaxf((float)(end - beg), 1.0f);
    }
    __syncthreads();
    if (tid < 50) {
        float a = b1[tid];
        for (int k = 0; k < HID; ++k) a += W1[tid * HID + k] * sp[k];
        h1[tid] = fmaxf(a, 0.f);
    }
    __syncthreads();
    if (tid < 25) {
        float a = b2[tid];
        for (int k = 0; k < 50; ++k) a += W2[tid * 50 + k] * h1[k];
        h2[tid] = fmaxf(a, 0.f);
    }
    __syncthreads();
    if (tid == 0) {
        float a = b3[0];
        for (int k = 0; k < 25; ++k) a += W3[k] * h2[k];
        out[g] = a;
    }
}

extern "C" void kernel_launch(void* const* d_in, const int* in_sizes, int n_in,
                              void* d_out, int out_size, void* d_ws, size_t ws_size,
                              hipStream_t stream) {
    const float* x      = (const float*)d_in[0];
    const int*   ei     = (const int*)d_in[1];
    const int*   batch  = (const int*)d_in[2];
    const float* preW0  = (const float*)d_in[3];
    const float* preb0  = (const float*)d_in[4];
    const float* postW0 = (const float*)d_in[5];
    const float* postb0 = (const float*)d_in[6];
    const float* linW0  = (const float*)d_in[7];
    const float* linb0  = (const float*)d_in[8];
    const float* gamma0 = (const float*)d_in[9];
    const float* beta0  = (const float*)d_in[10];
    const float* preW1  = (const float*)d_in[11];
    const float* preb1  = (const float*)d_in[12];
    const float* postW1 = (const float*)d_in[13];
    const float* postb1 = (const float*)d_in[14];
    const float* linW1  = (const float*)d_in[15];
    const float* linb1  = (const float*)d_in[16];
    const float* gamma1 = (const float*)d_in[17];
    const float* beta1  = (const float*)d_in[18];
    const float* mW1    = (const float*)d_in[19];
    const float* mb1    = (const float*)d_in[20];
    const float* mW2    = (const float*)d_in[21];
    const float* mb2    = (const float*)d_in[22];
    const float* mW3    = (const float*)d_in[23];
    const float* mb3    = (const float*)d_in[24];
    float* out = (float*)d_out;
    (void)in_sizes; (void)n_in; (void)out_size; (void)ws_size;

    char* ws = (char*)d_ws;
    size_t off = 0;
    auto alloc = [&](size_t bytes) -> void* {
        void* p = ws + off;
        off += (bytes + 255) & ~(size_t)255;
        return p;
    };
    // zero-region (one memset): deg, cursor, bnacc0, bnacc1
    int*   deg     = (int*)alloc((size_t)NN * 4);
    int*   cursor  = (int*)alloc((size_t)NN * 4);
    float* bnacc0  = (float*)alloc(128 * 4);
    float* bnacc1  = (float*)alloc(128 * 4);
    size_t zero_bytes = off;
    int*   offsets = (int*)alloc((size_t)(NN + 1) * 4);
    int*   csr_src = (int*)alloc((size_t)EE * 4);
    float* scal    = (float*)alloc(64);
    float* preWt0  = (float*)alloc((size_t)32 * 80 * 4);
    float* preWt1  = (float*)alloc((size_t)100 * 256 * 4);
    float* Wx0     = (float*)alloc((size_t)4 * 256 * 4);
    float* Wid0    = (float*)alloc((size_t)16 * 256 * 4);
    float* Wamp0   = (float*)alloc((size_t)16 * 256 * 4);
    float* Watt0   = (float*)alloc((size_t)16 * 256 * 4);
    float* Wx1     = (float*)alloc((size_t)13 * 256 * 4);
    float* Wid1    = (float*)alloc((size_t)52 * 256 * 4);
    float* Wamp1   = (float*)alloc((size_t)52 * 256 * 4);
    float* Watt1   = (float*)alloc((size_t)52 * 256 * 4);
    float* Lt0     = (float*)alloc((size_t)13 * 256 * 4);
    float* Lt1     = (float*)alloc((size_t)13 * 256 * 4);
    float* Cbuf    = (float*)alloc((size_t)NN * 256 * 4);
    float* Pbuf    = (float*)alloc((size_t)NN * 256 * 4);
    float* h1buf   = (float*)alloc((size_t)NN * HID * 4);
    float* h2buf   = (float*)alloc((size_t)NN * HID * 4);

    const int* src = ei;
    const int* dst = ei + EE;

    hipMemsetAsync(ws, 0, zero_bytes, stream);

    k_pack<<<dim3(100, 12), 256, 0, stream>>>(preW0, preW1, postW0, postW1, linW0, linW1,
                                              preWt0, preWt1, Wx0, Wid0, Wamp0, Watt0,
                                              Wx1, Wid1, Wamp1, Watt1, Lt0, Lt1);
    k_deg<<<EE / 256, 256, 0, stream>>>(dst, deg);
    k_scan<<<1, 1024, 0, stream>>>(deg, offsets, scal);
    k_fill<<<EE / 256, 256, 0, stream>>>(src, dst, offsets, cursor, csr_src);

    // ---- conv0 (F=16, TFPG=TFPL=80, EP=3) ----
    k_gemm_CP<INDIM, 80, 80, false><<<NN / 16, 256, 0, stream>>>(
        x, preWt0, preb0, nullptr, nullptr, nullptr, Cbuf, Pbuf);
    k_conv<INDIM, 80, 80, 3, 4, 4, true, false><<<NN / 8, 256, 0, stream>>>(
        x, Cbuf, Pbuf, offsets, csr_src, scal, Wx0, Wid0, Wamp0, Watt0, postb0, Lt0, linb0,
        nullptr, nullptr, nullptr, h1buf, bnacc0);

    // ---- conv1 (F=50, TFPG=256, TFPL=252, EP=1); BN0+ReLU fused into loads ----
    k_gemm_CP<HID, 250, 256, true><<<NN / 16, 256, 0, stream>>>(
        h1buf, preWt1, preb1, bnacc0, gamma0, beta0, Cbuf, Pbuf);
    k_conv<HID, 256, 252, 1, 13, 13, false, true><<<NN / 8, 256, 0, stream>>>(
        h1buf, Cbuf, Pbuf, offsets, csr_src, scal, Wx1, Wid1, Wamp1, Watt1, postb1, Lt1, linb1,
        bnacc0, gamma0, beta0, h2buf, bnacc1);

    // ---- BN1+ReLU fused into pooling + head ----
    k_head<<<NGROUPS, 64, 0, stream>>>(h2buf, batch, bnacc1, gamma1, beta1,
                                       mW1, mb1, mW2, mb2, mW3, mb3, out);
}